// Round 14
// baseline (48.273 us; speedup 1.0000x reference)
//
#include <hip/hip_runtime.h>
#include <hip/hip_bf16.h>
#include <math.h>

// QConv2d: new_rho = kron(Ux,Uy) @ rho @ kron(Ux,Uy)^T
// Per 64x64 tile T: O = W T W^T, W = Ufx (x) Ufy (64x64, shared, bf16).
//
// r14 = r13 + REGISTER-PINNED staging loads.
// r13's VGPR=44 proved the compiler sank each 1KB load into the convert
// loop (16 serial vmcnt(0) round-trips per wave) despite sched_barrier(0).
// asm volatile "+v" pins force all 16 float4 results to be materialized
// before any consumer -> 16 loads in flight per wave, progressive
// vmcnt(15..0) drain. Everything else identical to r13 (passed, 0.031):
//  - grid 1024 x 256thr; block = (b, bi, ch2) = 64 rows x 256 cols.
//  - LDS: 2 pair-tiles [64][128] bf16 chunk-swizzled + 4 Q-strips = 40KB
//    -> 4 blocks/CU (16 waves/CU).
//  - per wave one 64x64 tile: GEMM1 Q=W@T^T, Q->bf16 strip, GEMM2
//    O^T=Q@W^T, full-sector float4 stores.

typedef __attribute__((ext_vector_type(8))) short short8_t;  // 8 bf16
typedef __attribute__((ext_vector_type(4))) float f32x4;

__global__ void setup_w(const float* __restrict__ phi_x,
                        const float* __restrict__ phi_y,
                        unsigned short* __restrict__ W) {
    __shared__ float U[2][64];
    const int t = threadIdx.x;
    if (t < 2) {
        const float* phi = (t == 0) ? phi_x : phi_y;
        float Um[8][8];
#pragma unroll
        for (int i = 0; i < 8; ++i)
#pragma unroll
            for (int j = 0; j < 8; ++j) Um[i][j] = (i == j) ? 1.0f : 0.0f;
        int idx = 0;
#pragma unroll
        for (int i = 1; i < 8; ++i) {
#pragma unroll
            for (int j = i; j >= 1; --j) {
                const float c = cosf(phi[idx]);
                const float s = sinf(phi[idx]);
#pragma unroll
                for (int m = 0; m < 8; ++m) {
                    const float a = Um[j - 1][m], b = Um[j][m];
                    Um[j - 1][m] = c * a + s * b;
                    Um[j][m]     = -s * a + c * b;
                }
                ++idx;
            }
        }
#pragma unroll
        for (int i = 0; i < 8; ++i)
#pragma unroll
            for (int j = 0; j < 8; ++j) U[t][i * 8 + j] = Um[i][j];
    }
    __syncthreads();
    const int xi = t >> 3, yi = t & 7;
#pragma unroll
    for (int j = 0; j < 64; ++j) {
        const int xj = j >> 3, yj = j & 7;
        const float w = U[0][xi * 8 + xj] * U[1][yi * 8 + yj];
        __hip_bfloat16 h = __float2bfloat16(w);
        W[t * 64 + j] = *reinterpret_cast<const unsigned short*>(&h);
    }
}

__device__ __forceinline__ unsigned short bf16bits(float v) {
    __hip_bfloat16 h = __float2bfloat16(v);
    return *reinterpret_cast<const unsigned short*>(&h);
}

__global__ __launch_bounds__(256) void qconv_mfma4(const float* __restrict__ rho,
                                                   const unsigned short* __restrict__ Wg,
                                                   float* __restrict__ out) {
    extern __shared__ __align__(16) unsigned short L[];  // 20480 shorts = 40KB
    // [0,16384): 2 pair-tiles x [64 rows][128 cols] bf16, chunk-swizzled
    // [16384,20480): 4 x 1024-short Q-strips
    const int t = threadIdx.x;
    const int w = t >> 6;   // wave 0..3
    const int l = t & 63;

    const int uid = blockIdx.x;
    const int ch2 = uid & 3;          // 256-col chunk
    const int bi  = (uid >> 2) & 15;  // row block (bx1*4+by1)
    const int b   = uid >> 6;

    const size_t B0   = (size_t)b << 20;
    const int    rowb = (bi >> 2) * 256 + (bi & 3) * 8;

    // ---------------- stage: 16 full-row 1KB-contiguous loads ----------------
    const float* __restrict__ src = rho + B0 + ch2 * 256 + 4 * l;
    float4 v[16];
#pragma unroll
    for (int j = 0; j < 16; ++j) {
        const int rt   = j * 4 + w;                       // T-row
        const int grow = rowb + (rt >> 3) * 32 + (rt & 7);
        v[j] = *reinterpret_cast<const float4*>(src + (size_t)grow * 1024);
    }
    // PIN all 16 results: compiler cannot sink the loads past these -> all
    // 16 vector loads issue before the first convert (true MLP).
#pragma unroll
    for (int j = 0; j < 16; ++j)
        asm volatile("" : "+v"(v[j].x), "+v"(v[j].y), "+v"(v[j].z), "+v"(v[j].w));

    {
        const int u0 = (l >> 2) & 1;                         // pair-tile
        const int pc = ((l >> 1) & 1) * 8 + ((l >> 3) & 7);  // chunk pre-swizzle
        const int el = (l & 1) * 4;                          // elem within chunk
#pragma unroll
        for (int j = 0; j < 16; ++j) {
            const int rt = j * 4 + w;
            ushort4 h;
            h.x = bf16bits(v[j].x); h.y = bf16bits(v[j].y);
            h.z = bf16bits(v[j].z); h.w = bf16bits(v[j].w);
            *reinterpret_cast<ushort4*>(
                &L[(u0 * 64 + rt) * 128 + ((pc ^ (rt & 15)) << 3) + el]) = h;
        }
    }
    __syncthreads();

    // ---------------- compute: wave w = tile (bx2=ch2, by2=w) ----------------
    const int ln = l & 15;
    const int q  = l >> 4;
    const unsigned short* __restrict__ Tp = &L[(w >> 1) * 8192];
    unsigned short* __restrict__ Qs       = &L[16384 + w * 1024];
    const int wc  = (w & 1) * 8;
    const int bx2 = ch2, by2 = w;

#pragma unroll
    for (int m = 0; m < 4; ++m) {
        // GEMM1: Q16 = W[16m..16m+16) @ T^T
        const short8_t AW0 = *reinterpret_cast<const short8_t*>(
            Wg + (16 * m + ln) * 64 + q * 8);
        const short8_t AW1 = *reinterpret_cast<const short8_t*>(
            Wg + (16 * m + ln) * 64 + 32 + q * 8);
        f32x4 acc[4];
#pragma unroll
        for (int tc = 0; tc < 4; ++tc) {
            const int prow = 16 * tc + ln;
            const short8_t BT0 = *reinterpret_cast<const short8_t*>(
                Tp + prow * 128 + (((wc + 0 + q) ^ (prow & 15)) << 3));
            const short8_t BT1 = *reinterpret_cast<const short8_t*>(
                Tp + prow * 128 + (((wc + 4 + q) ^ (prow & 15)) << 3));
            f32x4 c = {0.0f, 0.0f, 0.0f, 0.0f};
            c = __builtin_amdgcn_mfma_f32_16x16x32_bf16(AW0, BT0, c, 0, 0, 0);
            c = __builtin_amdgcn_mfma_f32_16x16x32_bf16(AW1, BT1, c, 0, 0, 0);
            acc[tc] = c;
        }

        // Q16 -> bf16 LDS strip (wave-private)
#pragma unroll
        for (int tc = 0; tc < 4; ++tc)
#pragma unroll
            for (int i = 0; i < 4; ++i) {
                const int qrow = 4 * q + i;
                const int qcol = 16 * tc + ln;
                Qs[qrow * 64 + (((qcol >> 3) ^ (qrow & 7)) << 3) + (qcol & 7)] =
                    bf16bits(acc[tc][i]);
            }

        // GEMM2: O16^T = Q16 @ W^T ; direct full-sector float4 stores
        const short8_t AQ0 = *reinterpret_cast<const short8_t*>(
            Qs + ln * 64 + (((0 + q) ^ (ln & 7)) << 3));
        const short8_t AQ1 = *reinterpret_cast<const short8_t*>(
            Qs + ln * 64 + (((4 + q) ^ (ln & 7)) << 3));
#pragma unroll
        for (int tc = 0; tc < 4; ++tc) {
            const short8_t BW0 = *reinterpret_cast<const short8_t*>(
                Wg + (16 * tc + ln) * 64 + q * 8);
            const short8_t BW1 = *reinterpret_cast<const short8_t*>(
                Wg + (16 * tc + ln) * 64 + 32 + q * 8);
            f32x4 o = {0.0f, 0.0f, 0.0f, 0.0f};
            o = __builtin_amdgcn_mfma_f32_16x16x32_bf16(AQ0, BW0, o, 0, 0, 0);
            o = __builtin_amdgcn_mfma_f32_16x16x32_bf16(AQ1, BW1, o, 0, 0, 0);

            const int grow = rowb + (2 * tc + (ln >> 3)) * 32 + (ln & 7);
            const int c0   = 16 * m + 4 * q;
            const int gcol = bx2 * 256 + (c0 >> 3) * 32 + by2 * 8 + (c0 & 7);
            *reinterpret_cast<float4*>(out + B0 + (size_t)grow * 1024 + gcol) =
                make_float4(o[0], o[1], o[2], o[3]);
        }
    }
}

extern "C" void kernel_launch(void* const* d_in, const int* in_sizes, int n_in,
                              void* d_out, int out_size, void* d_ws, size_t ws_size,
                              hipStream_t stream) {
    const float* rho   = (const float*)d_in[0];
    const float* phi_x = (const float*)d_in[1];
    const float* phi_y = (const float*)d_in[2];
    float* out = (float*)d_out;
    unsigned short* W = (unsigned short*)d_ws;

    setup_w<<<1, 64, 0, stream>>>(phi_x, phi_y, W);
    qconv_mfma4<<<1024, 256, 40960, stream>>>(rho, W, out);
}